// Round 4
// baseline (688.693 us; speedup 1.0000x reference)
//
#include <hip/hip_runtime.h>

// Problem constants (fixed by setup_inputs in the reference)
constexpr int FRAME   = 1024;
constexpr int HOP     = 512;
constexpr int BATCH   = 64;
constexpr int SAMPLES = 1 << 20;
constexpr int NSEG    = SAMPLES / HOP - FRAME / HOP + 1;   // 2047
constexpr int NHOP    = SAMPLES / HOP;                     // 2048
constexpr int F4      = FRAME / 4;      // 256 float4 per frame
constexpr int H4      = HOP / 4;        // 128 float4 per hop
constexpr int S4      = SAMPLES / 4;    // 262144 float4 per batch row

// Native vector type — required for __builtin_nontemporal_*
typedef float f32x4 __attribute__((ext_vector_type(4)));

// Hop-centric with 4x ILP: each thread owns 4 float4s of x (1KB-coalesced per
// access k: idx = blk*1024 + k*256 + tid), reads each exactly once, and feeds
// the two frames containing each.
//   x float4 index j4 = h*H4 + r  (h = hop, r in [0,H4))
//   -> frame s=h,   f4 = r        (skip when h == NHOP-1)
//   -> frame s=h-1, f4 = r + H4   (skip when h == 0)
__global__ __launch_bounds__(256) void seg_win_hop4_kernel(
    const f32x4* __restrict__ x,
    const f32x4* __restrict__ win,
    const f32x4* __restrict__ pre,
    const f32x4* __restrict__ post,
    f32x4* __restrict__ out)
{
    const size_t base = (size_t)blockIdx.x * 1024;   // block covers 1024 float4
    // S4 = 2^18 is divisible by 1024 -> a block never crosses a batch row.

    // Issue all 4 loads first (independent, 1KB-coalesced each)
    f32x4 xv[4];
    size_t gid[4];
#pragma unroll
    for (int k = 0; k < 4; ++k) {
        gid[k] = base + (size_t)k * 256 + threadIdx.x;
        xv[k]  = __builtin_nontemporal_load(&x[gid[k]]);
    }

#pragma unroll
    for (int k = 0; k < 4; ++k) {
        const int b  = (int)(gid[k] >> 18);          // / S4
        const int j4 = (int)(gid[k] & (S4 - 1));     // % S4
        const int h  = j4 >> 7;                      // wave-uniform
        const int r  = j4 & (H4 - 1);

        const size_t out_row_base = (size_t)b * NSEG;

        if (h != NHOP - 1) {                         // store 1: frame s = h
            const int s = h;
            const f32x4* __restrict__ w =
                (s == 0) ? pre : (s == NSEG - 1) ? post : win;
            const f32x4 o = xv[k] * w[r];
            __builtin_nontemporal_store(o, &out[(out_row_base + s) * F4 + r]);
        }
        if (h != 0) {                                // store 2: frame s = h-1
            const int s = h - 1;
            const f32x4* __restrict__ w =
                (s == 0) ? pre : (s == NSEG - 1) ? post : win;
            const f32x4 o = xv[k] * w[r + H4];
            __builtin_nontemporal_store(o, &out[(out_row_base + s) * F4 + r + H4]);
        }
    }
}

extern "C" void kernel_launch(void* const* d_in, const int* in_sizes, int n_in,
                              void* d_out, int out_size, void* d_ws, size_t ws_size,
                              hipStream_t stream)
{
    // setup_inputs order: x, window, prewindow, postwindow, hop_size, frame_size
    const f32x4* x    = (const f32x4*)d_in[0];
    const f32x4* win  = (const f32x4*)d_in[1];
    const f32x4* pre  = (const f32x4*)d_in[2];
    const f32x4* post = (const f32x4*)d_in[3];
    f32x4* out        = (f32x4*)d_out;

    // BATCH * S4 / 1024 = 16384 blocks of 256 threads
    dim3 grid((BATCH * (size_t)S4) / 1024);
    dim3 block(256);
    seg_win_hop4_kernel<<<grid, block, 0, stream>>>(x, win, pre, post, out);
}